// Round 3
// 1246.964 us; speedup vs baseline: 1.2343x; 1.2343x over previous
//
#include <hip/hip_runtime.h>
#include <hip/hip_bf16.h>
#include <stdint.h>

#define M_DIM 8192
#define K_DIM 4096
#define N_DIM 11008
#define BM 256
#define BN 256
#define BK 64
#define NKT (K_DIM / BK)  // 64 K-tiles

typedef __bf16 bf16x8 __attribute__((ext_vector_type(8)));
typedef float f32x4 __attribute__((ext_vector_type(4)));
typedef short short8 __attribute__((ext_vector_type(8)));

__device__ __forceinline__ ushort f32_to_bf16_rne(float f) {
    uint32_t u = __builtin_bit_cast(uint32_t, f);
    return (ushort)((u + 0x7fffu + ((u >> 16) & 1u)) >> 16);
}

// x fp32 -> bf16, 8 elems/thread
__global__ __launch_bounds__(256) void cvt_x_kernel(const float* __restrict__ x,
                                                    ushort* __restrict__ o, int n8) {
    int t = blockIdx.x * 256 + threadIdx.x;
    if (t >= n8) return;
    const float4* src = (const float4*)x + (size_t)t * 2;
    float4 a = src[0], b = src[1];
    union { ushort u[8]; short8 v; } r;
    r.u[0] = f32_to_bf16_rne(a.x); r.u[1] = f32_to_bf16_rne(a.y);
    r.u[2] = f32_to_bf16_rne(a.z); r.u[3] = f32_to_bf16_rne(a.w);
    r.u[4] = f32_to_bf16_rne(b.x); r.u[5] = f32_to_bf16_rne(b.y);
    r.u[6] = f32_to_bf16_rne(b.z); r.u[7] = f32_to_bf16_rne(b.w);
    *(short8*)(o + (size_t)t * 8) = r.v;
}

// weight int32 (harness widens int8->int32) -> bf16 (exact), 8 elems/thread
__global__ __launch_bounds__(256) void cvt_w_kernel(const int* __restrict__ w,
                                                    ushort* __restrict__ o, int n8) {
    int t = blockIdx.x * 256 + threadIdx.x;
    if (t >= n8) return;
    const int4* src = (const int4*)w + (size_t)t * 2;
    int4 a = src[0], b = src[1];
    union { ushort u[8]; short8 v; } r;
    r.u[0] = f32_to_bf16_rne((float)a.x); r.u[1] = f32_to_bf16_rne((float)a.y);
    r.u[2] = f32_to_bf16_rne((float)a.z); r.u[3] = f32_to_bf16_rne((float)a.w);
    r.u[4] = f32_to_bf16_rne((float)b.x); r.u[5] = f32_to_bf16_rne((float)b.y);
    r.u[6] = f32_to_bf16_rne((float)b.z); r.u[7] = f32_to_bf16_rne((float)b.w);
    *(short8*)(o + (size_t)t * 8) = r.v;
}

// C = A(MxK) * B(NxK)^T ; epilogue y = acc*scales[n] + bias[n]
// 256x256 tile, BK=64, 8 waves (2Mx4N), 4-phase/tile schedule, counted vmcnt(6).
// LDS: double-buffered 256x64 bf16 tiles, k-groups XOR-swizzled by row&7.
// STAGING SAFETY RULE: a region is staged only in a phase STRICTLY AFTER its
// last ds_read phase (read->MFMA reg dependency forces each wave's ds_reads to
// complete before it reaches the phase-end barrier).
//   A rows {0-63 u 128-191} read P1; {64-127 u 192-255} read P3.
//   B rows: blo = wn*32+[0,32) all in H0, read P1; bhi = +128 in H1, read P2.
//   => P1 stages A-hi(T+1) (other buf; last read prev tile P3)
//      P2 stages B-lo(T+2)  (this buf; last read P1)
//      P3 stages B-hi(T+2)  (this buf; last read P2)
//      P4 stages A-lo(T+2)  (this buf; last read P3)
__global__ __launch_bounds__(512, 2) void gemm_bf16_kernel(
    const ushort* __restrict__ A, const ushort* __restrict__ B,
    const float* __restrict__ scales, const float* __restrict__ bias,
    float* __restrict__ out) {
    __shared__ ushort sA[2 * BM * BK];  // 64 KB
    __shared__ ushort sB[2 * BN * BK];  // 64 KB

    const int t = threadIdx.x;
    const int l = t & 63;
    const int w = t >> 6;    // 0..7
    const int wm = w >> 2;   // 0..1
    const int wn = w & 3;    // 0..3

    // XCD-aware swizzle: grid = 43*32 = 1376 = 8 * 172 (exactly divisible)
    const int bid = blockIdx.x;
    const int sw = (bid & 7) * 172 + (bid >> 3);
    const int bn = sw % 43;
    const int bm = sw / 43;
    const int m0 = bm * BM;
    const int n0 = bn * BN;

    // ---- staging source addresses (pre-swizzled k-group) ----
    // wave w covers flat LDS elems [w*512 + lane*8): row r = t>>3 (+64 for 2nd
    // load, +128 for H=1 — both keep r&7), stored group = t&7,
    // logical source group = (t&7) ^ (r&7)
    const int r8 = t >> 3;                    // 0..63
    const int gsw = (t & 7) ^ (r8 & 7);
    const ushort* aSrc = A + (size_t)(m0 + r8) * K_DIM + gsw * 8;
    const ushort* bSrc = B + (size_t)(n0 + r8) * K_DIM + gsw * 8;
    const int ldsW = w * 512;

    // ---- fragment LDS addressing ----
    const int rowA = wm * 128 + (l & 15);     // + mf*16  (mf 0..7)
    const int rowB = wn * 32 + (l & 15);      // + nf*16 (blo), +128 (bhi)
    // logical k-group lg = ks*4 + (l>>4); stored at lg ^ (row&7), row&7 == l&7
    const int cg0 = (((l >> 4) + 0) ^ (l & 7)) * 8;  // ks = 0
    const int cg1 = (((l >> 4) + 4) ^ (l & 7)) * 8;  // ks = 1

    bf16x8 af[8];   // A frags: Mlo (P1/P2), overwritten with Mhi (P3/P4)
    bf16x8 blo[4];  // B frags nf 0..1 (rows wn*32+{0,16}), live P1..P3
    bf16x8 bhi[4];  // B frags nf 2..3 (rows 128+wn*32+{0,16}), live P2..P4
    f32x4 acc[8][4] = {};

#define STAGE(SRC, DST, H, KT, BUFO)                                              \
    do {                                                                          \
        const ushort* _s = (SRC) + (size_t)((H) * 128) * K_DIM + (KT) * BK;       \
        ushort* _d = (DST) + (BUFO) + (H) * 8192 + ldsW;                          \
        __builtin_amdgcn_global_load_lds(                                         \
            (__attribute__((address_space(1))) void*)_s,                          \
            (__attribute__((address_space(3))) void*)_d, 16, 0, 0);               \
        __builtin_amdgcn_global_load_lds(                                         \
            (__attribute__((address_space(1))) void*)(_s + (size_t)64 * K_DIM),   \
            (__attribute__((address_space(3))) void*)(_d + 4096), 16, 0, 0);      \
    } while (0)

// vmcnt bookkeeping: per tile, issue order is [A-hi(T+1), B-lo(T+2),
// B-hi(T+2), A-lo(T+2)] = 8 loads. Carried into each tile: 6 loads =
// {B-lo,B-hi,A-lo}(T+1). At P4 vmcnt(6): retire 8 oldest = those 6 + A-hi(T+1)
// => tile T+1 fully resident (in-order retirement). Tail stages clamped
// dummies into dead regions to keep the count uniform.
#define TILE_BODY(T, CB)                                                            \
    do {                                                                            \
        const int _k1 = ((T) + 1 < NKT) ? (T) + 1 : NKT - 1;                        \
        const int _k2 = ((T) + 2 < NKT) ? (T) + 2 : NKT - 1;                        \
        const int _cb = (CB) * (BM * BK);                                           \
        /* ---- P1: read A-lo frags + blo; MFMA (Mlo x Nlo); stage A-hi(t+1) */     \
        _Pragma("unroll") for (int mf = 0; mf < 4; ++mf) {                          \
            af[mf * 2 + 0] = *(const bf16x8*)(sA + _cb + (rowA + mf * 16) * BK + cg0); \
            af[mf * 2 + 1] = *(const bf16x8*)(sA + _cb + (rowA + mf * 16) * BK + cg1); \
        }                                                                           \
        _Pragma("unroll") for (int nf = 0; nf < 2; ++nf) {                          \
            blo[nf * 2 + 0] = *(const bf16x8*)(sB + _cb + (rowB + nf * 16) * BK + cg0); \
            blo[nf * 2 + 1] = *(const bf16x8*)(sB + _cb + (rowB + nf * 16) * BK + cg1); \
        }                                                                           \
        STAGE(aSrc, sA, 1, _k1, ((CB) ^ 1) * (BM * BK));                            \
        __builtin_amdgcn_s_barrier();                                               \
        asm volatile("s_waitcnt lgkmcnt(0)" ::: "memory");                          \
        __builtin_amdgcn_s_setprio(1);                                              \
        _Pragma("unroll") for (int mf = 0; mf < 4; ++mf)                            \
        _Pragma("unroll") for (int nf = 0; nf < 2; ++nf) {                          \
            acc[mf][nf] = __builtin_amdgcn_mfma_f32_16x16x32_bf16(                  \
                af[mf * 2 + 0], blo[nf * 2 + 0], acc[mf][nf], 0, 0, 0);             \
            acc[mf][nf] = __builtin_amdgcn_mfma_f32_16x16x32_bf16(                  \
                af[mf * 2 + 1], blo[nf * 2 + 1], acc[mf][nf], 0, 0, 0);             \
        }                                                                           \
        __builtin_amdgcn_s_setprio(0);                                              \
        __builtin_amdgcn_s_barrier();                                               \
        /* ---- P2: read bhi; MFMA (Mlo x Nhi); stage B-lo(t+2) ---- */             \
        _Pragma("unroll") for (int nf = 0; nf < 2; ++nf) {                          \
            bhi[nf * 2 + 0] = *(const bf16x8*)(sB + _cb + (rowB + 128 + nf * 16) * BK + cg0); \
            bhi[nf * 2 + 1] = *(const bf16x8*)(sB + _cb + (rowB + 128 + nf * 16) * BK + cg1); \
        }                                                                           \
        STAGE(bSrc, sB, 0, _k2, (CB) * (BM * BK));                                  \
        __builtin_amdgcn_s_barrier();                                               \
        asm volatile("s_waitcnt lgkmcnt(0)" ::: "memory");                          \
        __builtin_amdgcn_s_setprio(1);                                              \
        _Pragma("unroll") for (int mf = 0; mf < 4; ++mf)                            \
        _Pragma("unroll") for (int nf = 0; nf < 2; ++nf) {                          \
            acc[mf][nf + 2] = __builtin_amdgcn_mfma_f32_16x16x32_bf16(              \
                af[mf * 2 + 0], bhi[nf * 2 + 0], acc[mf][nf + 2], 0, 0, 0);         \
            acc[mf][nf + 2] = __builtin_amdgcn_mfma_f32_16x16x32_bf16(              \
                af[mf * 2 + 1], bhi[nf * 2 + 1], acc[mf][nf + 2], 0, 0, 0);         \
        }                                                                           \
        __builtin_amdgcn_s_setprio(0);                                              \
        __builtin_amdgcn_s_barrier();                                               \
        /* ---- P3: read A-hi frags (reuse af); MFMA (Mhi x Nlo); stage B-hi(t+2) */\
        _Pragma("unroll") for (int mf = 0; mf < 4; ++mf) {                          \
            af[mf * 2 + 0] = *(const bf16x8*)(sA + _cb + (rowA + (mf + 4) * 16) * BK + cg0); \
            af[mf * 2 + 1] = *(const bf16x8*)(sA + _cb + (rowA + (mf + 4) * 16) * BK + cg1); \
        }                                                                           \
        STAGE(bSrc, sB, 1, _k2, (CB) * (BM * BK));                                  \
        __builtin_amdgcn_s_barrier();                                               \
        asm volatile("s_waitcnt lgkmcnt(0)" ::: "memory");                          \
        __builtin_amdgcn_s_setprio(1);                                              \
        _Pragma("unroll") for (int mf = 0; mf < 4; ++mf)                            \
        _Pragma("unroll") for (int nf = 0; nf < 2; ++nf) {                          \
            acc[mf + 4][nf] = __builtin_amdgcn_mfma_f32_16x16x32_bf16(              \
                af[mf * 2 + 0], blo[nf * 2 + 0], acc[mf + 4][nf], 0, 0, 0);         \
            acc[mf + 4][nf] = __builtin_amdgcn_mfma_f32_16x16x32_bf16(              \
                af[mf * 2 + 1], blo[nf * 2 + 1], acc[mf + 4][nf], 0, 0, 0);         \
        }                                                                           \
        __builtin_amdgcn_s_setprio(0);                                              \
        __builtin_amdgcn_s_barrier();                                               \
        /* ---- P4: no reads; MFMA (Mhi x Nhi); stage A-lo(t+2); counted vmcnt */   \
        STAGE(aSrc, sA, 0, _k2, (CB) * (BM * BK));                                  \
        asm volatile("s_waitcnt vmcnt(6)" ::: "memory");                            \
        __builtin_amdgcn_s_barrier();                                               \
        __builtin_amdgcn_s_setprio(1);                                              \
        _Pragma("unroll") for (int mf = 0; mf < 4; ++mf)                            \
        _Pragma("unroll") for (int nf = 0; nf < 2; ++nf) {                          \
            acc[mf + 4][nf + 2] = __builtin_amdgcn_mfma_f32_16x16x32_bf16(          \
                af[mf * 2 + 0], bhi[nf * 2 + 0], acc[mf + 4][nf + 2], 0, 0, 0);     \
            acc[mf + 4][nf + 2] = __builtin_amdgcn_mfma_f32_16x16x32_bf16(          \
                af[mf * 2 + 1], bhi[nf * 2 + 1], acc[mf + 4][nf + 2], 0, 0, 0);     \
        }                                                                           \
        __builtin_amdgcn_s_setprio(0);                                              \
        __builtin_amdgcn_s_barrier();                                               \
    } while (0)

    // ---- prologue: tile 0 fully + {B-lo,B-hi,A-lo}(1); keep 6 in flight ----
    STAGE(aSrc, sA, 0, 0, 0);        // A-lo(0)
    STAGE(aSrc, sA, 1, 0, 0);        // A-hi(0)
    STAGE(bSrc, sB, 0, 0, 0);        // B-lo(0)
    STAGE(bSrc, sB, 1, 0, 0);        // B-hi(0)
    STAGE(bSrc, sB, 0, 1, BM * BK);  // B-lo(1)
    STAGE(bSrc, sB, 1, 1, BM * BK);  // B-hi(1)
    STAGE(aSrc, sA, 0, 1, BM * BK);  // A-lo(1)
    asm volatile("s_waitcnt vmcnt(6)" ::: "memory");  // tile 0 resident
    __builtin_amdgcn_s_barrier();

    for (int kt = 0; kt < NKT; kt += 2) {
        TILE_BODY(kt, 0);
        TILE_BODY(kt + 1, 1);
    }

#undef TILE_BODY
#undef STAGE

    // Drain the 6 in-flight tail dummy loads BEFORE s_endpgm: an LDS-targeting
    // global_load_lds still in flight when the block retires could land in a
    // newly-scheduled block's LDS allocation (timing-dependent corruption).
    asm volatile("s_waitcnt vmcnt(0)" ::: "memory");

    // ---- epilogue: y = acc * scales[n] + bias[n] ----
    // C/D layout (16x16x32): col = lane&15, row = (lane>>4)*4 + reg
    const int mBase = m0 + wm * 128 + (l >> 4) * 4;
    const int nBase = n0 + wn * 32 + (l & 15);
#pragma unroll
    for (int nf = 0; nf < 4; ++nf) {
        const int n = nBase + (nf & 1) * 16 + (nf >> 1) * 128;
        const float s = scales[n];
        const float bz = bias[n];
#pragma unroll
        for (int mf = 0; mf < 8; ++mf) {
            const int m = mBase + mf * 16;
#pragma unroll
            for (int r2 = 0; r2 < 4; ++r2) {
                out[(size_t)(m + r2) * N_DIM + n] = acc[mf][nf][r2] * s + bz;
            }
        }
    }
}

extern "C" void kernel_launch(void* const* d_in, const int* in_sizes, int n_in,
                              void* d_out, int out_size, void* d_ws, size_t ws_size,
                              hipStream_t stream) {
    const float* x = (const float*)d_in[0];
    const int* wq = (const int*)d_in[1];
    const float* scales = (const float*)d_in[2];
    const float* bias = (const float*)d_in[3];
    float* out = (float*)d_out;

    const size_t x_elems = (size_t)M_DIM * K_DIM;  // 33,554,432
    const size_t w_elems = (size_t)N_DIM * K_DIM;  // 45,088,768
    const size_t need = (x_elems + w_elems) * sizeof(ushort);
    if (ws_size < need) return;  // workspace too small — fail loudly via mismatch

    ushort* xb = (ushort*)d_ws;
    ushort* wb = xb + x_elems;

    cvt_x_kernel<<<dim3((int)(x_elems / 8 / 256)), dim3(256), 0, stream>>>(x, xb, (int)(x_elems / 8));
    cvt_w_kernel<<<dim3((int)(w_elems / 8 / 256)), dim3(256), 0, stream>>>(wq, wb, (int)(w_elems / 8));

    gemm_bf16_kernel<<<dim3((N_DIM / BN) * (M_DIM / BM)), dim3(512), 0, stream>>>(
        xb, wb, scales, bias, out);
}